// Round 8
// baseline (834.283 us; speedup 1.0000x reference)
//
#include <hip/hip_runtime.h>
#include <cstdint>

typedef short bf16x8 __attribute__((ext_vector_type(8)));
typedef float f32x4  __attribute__((ext_vector_type(4)));

#define TOK     32        // tokens per block
#define PITCH   264       // ushorts/row (256 + 8 pad; 132 dw = 4 mod 32 -> b128 tiles banks)
#define WROWS   16        // code rows per wave-private chunk buffer
#define WSTRIDE (WROWS * PITCH)
#define MAXC    24

__device__ __forceinline__ unsigned short f2bf(float f) {
  unsigned u = __float_as_uint(f);
  return (unsigned short)((u + 0x7FFFu + ((u >> 16) & 1u)) >> 16);
}
__device__ __forceinline__ uint4 pack8(float4 a, float4 b) {
  uint4 u;
  u.x = (unsigned)f2bf(a.x) | ((unsigned)f2bf(a.y) << 16);
  u.y = (unsigned)f2bf(a.z) | ((unsigned)f2bf(a.w) << 16);
  u.z = (unsigned)f2bf(b.x) | ((unsigned)f2bf(b.y) << 16);
  u.w = (unsigned)f2bf(b.z) | ((unsigned)f2bf(b.w) << 16);
  return u;
}

// ---------------------------------------------------------------------------
// Prep: cb_bf = bf16(cb), ee = ||cb_k||^2. Block 0 zeroes global accumulators.
// ---------------------------------------------------------------------------
__global__ __launch_bounds__(256) void vq_prep(const float* __restrict__ cb,
                                               unsigned short* __restrict__ cb_bf,
                                               float* __restrict__ ee,
                                               float* __restrict__ acc2,
                                               int* __restrict__ done_ctr, int K) {
  if (blockIdx.x == 0 && threadIdx.x == 0) {
    acc2[0] = 0.f; acc2[1] = 0.f; *done_ctr = 0;
  }
  int wave = threadIdx.x >> 6, lane = threadIdx.x & 63;
  int k = blockIdx.x * 4 + wave;
  if (k >= K) return;
  float4 v = *reinterpret_cast<const float4*>(cb + (size_t)k * 256 + lane * 4);
  float s = v.x * v.x + v.y * v.y + v.z * v.z + v.w * v.w;
  #pragma unroll
  for (int off = 32; off; off >>= 1) s += __shfl_down(s, off, 64);
  ushort4 b;
  b.x = f2bf(v.x); b.y = f2bf(v.y); b.z = f2bf(v.z); b.w = f2bf(v.w);
  *reinterpret_cast<ushort4*>(cb_bf + (size_t)k * 256 + lane * 4) = b;
  if (lane == 0) ee[k] = s;
}

// ---------------------------------------------------------------------------
// Main: 256 thr (4 waves), TOK=32, grid N/32=1024 -> 4 blocks/CU (LDS 39.7 KB).
// Every wave holds BOTH A-sets (tokens 0..31) in registers and scans its own
// K-quarter (256 codes = 16 chunks of 16) in a WAVE-PRIVATE LDS buffer ->
// ZERO barriers in the K-loop (DS ops are wave-ordered). Per chunk: 8 B-frag
// reads -> 16 MFMAs. bf16 screen, quarter-local-amin gate (2-eps bound holds),
// exact fp32 rescore -> indices pure-fp32-derived.
// R6 lesson: no tight launch bound (spill catastrophe); (256,2) is permissive.
// ---------------------------------------------------------------------------
__global__ __launch_bounds__(256, 2) void vq_main(
    const float* __restrict__ z, const float* __restrict__ cb,
    const unsigned short* __restrict__ cb_bf, const float* __restrict__ ee,
    const float* __restrict__ mask,
    float* __restrict__ out_q, float* __restrict__ out_idx_f,
    float* __restrict__ out_loss, float* __restrict__ acc2,
    int* __restrict__ done_ctr, int nblocks, int K) {
  __shared__ __align__(16) unsigned short buf[4 * WSTRIDE];  // 33792 B
  __shared__ float ee_lds[1024];                             // 4096 B
  __shared__ float znorm[TOK];
  __shared__ int   ccnt[TOK];
  __shared__ unsigned short cand[TOK * MAXC];                // 1536 B
  __shared__ float red[8];
  __shared__ bool  last;

  const int t = threadIdx.x;
  const int n0 = blockIdx.x * TOK;
  const int q16 = t & 15;

  // ---- code norms into LDS ----
  ee_lds[t]       = ee[t];
  ee_lds[t + 256] = ee[t + 256];
  ee_lds[t + 512] = ee[t + 512];
  ee_lds[t + 768] = ee[t + 768];
  if (t < TOK) ccnt[t] = 0;

  // ---- stage z -> bf16 into buf rows 0..31; ||z|| ----
  #pragma unroll
  for (int pass = 0; pass < 2; ++pass) {
    int row = pass * 16 + (t >> 4);
    const float* zr = z + (size_t)(n0 + row) * 256;
    float ssq = 0.f;
    #pragma unroll
    for (int j = 0; j < 2; ++j) {
      float4 a = *reinterpret_cast<const float4*>(zr + q16 * 8 + j * 128);
      float4 b = *reinterpret_cast<const float4*>(zr + q16 * 8 + j * 128 + 4);
      ssq += a.x*a.x + a.y*a.y + a.z*a.z + a.w*a.w
           + b.x*b.x + b.y*b.y + b.z*b.z + b.w*b.w;
      *reinterpret_cast<uint4*>(&buf[row * PITCH + q16 * 8 + j * 128]) = pack8(a, b);
    }
    #pragma unroll
    for (int off = 1; off < 16; off <<= 1) ssq += __shfl_xor(ssq, off, 64);
    if (q16 == 0) znorm[row] = sqrtf(ssq);
  }
  __syncthreads();

  // ---- A fragments (both sets, tokens 0..31) into registers, all waves ----
  const int wv = t >> 6, lane = t & 63;
  const int quad = lane >> 4, l15 = lane & 15;
  bf16x8 afrag[2][8];
  float  znreg[2][4];
  #pragma unroll
  for (int s = 0; s < 2; ++s) {
    const unsigned short* za = &buf[(s * 16 + l15) * PITCH + quad * 8];
    #pragma unroll
    for (int kk = 0; kk < 8; ++kk)
      afrag[s][kk] = *reinterpret_cast<const bf16x8*>(za + kk * 32);
    #pragma unroll
    for (int r = 0; r < 4; ++r)
      znreg[s][r] = znorm[s * 16 + quad * 4 + r];
  }
  __syncthreads();  // all A-loads done before wave staging overwrites buf

  float amin[2][4];
  #pragma unroll
  for (int s = 0; s < 2; ++s)
    #pragma unroll
    for (int r = 0; r < 4; ++r) amin[s][r] = 3.4e38f;

  unsigned short* qbuf = &buf[wv * WSTRIDE];   // wave-private chunk buffer

  // ---- K-loop: 16 chunks x 16 codes, wave-private, NO barriers ----
  for (int lc = 0; lc < 16; ++lc) {
    const int kbase = wv * 256 + lc * 16;
    // stage 16 code rows (bf16): 4 rows of 16 lanes per pass, 4 passes
    #pragma unroll
    for (int pass = 0; pass < 4; ++pass) {
      int row = pass * 4 + (lane >> 4);       // 0..15
      const unsigned short* src = cb_bf + (size_t)(kbase + row) * 256;
      #pragma unroll
      for (int j = 0; j < 2; ++j) {
        uint4 v = *reinterpret_cast<const uint4*>(src + q16 * 8 + j * 128);
        *reinterpret_cast<uint4*>(&qbuf[row * PITCH + q16 * 8 + j * 128]) = v;
      }
    }
    // wave-ordered DS: reads below see this wave's writes; no __syncthreads
    f32x4 acc0 = (f32x4){0.f,0.f,0.f,0.f}, acc1 = (f32x4){0.f,0.f,0.f,0.f};
    #pragma unroll
    for (int kk = 0; kk < 8; ++kk) {
      bf16x8 b = *reinterpret_cast<const bf16x8*>(&qbuf[l15 * PITCH + quad * 8 + kk * 32]);
      acc0 = __builtin_amdgcn_mfma_f32_16x16x32_bf16(afrag[0][kk], b, acc0, 0, 0, 0);
      acc1 = __builtin_amdgcn_mfma_f32_16x16x32_bf16(afrag[1][kk], b, acc1, 0, 0, 0);
    }

    float e0  = ee_lds[kbase + l15];
    float en0 = sqrtf(e0);
    #pragma unroll
    for (int s = 0; s < 2; ++s) {
      #pragma unroll
      for (int r = 0; r < 4; ++r) {
        float d0 = e0 - 2.f * (s == 0 ? acc0[r] : acc1[r]);
        float w = d0;
        #pragma unroll
        for (int off = 1; off < 16; off <<= 1) w = fminf(w, __shfl_xor(w, off, 64));
        float am = fminf(amin[s][r], w);
        amin[s][r] = am;
        int tok = s * 16 + quad * 4 + r;
        // margin >= 2*eps(bf16 screen); quarter-local amin keeps the bound
        if (d0 <= am + 1.5f + 0.002f * znreg[s][r] * en0) {
          int sl = atomicAdd(&ccnt[tok], 1);
          if (sl < MAXC) cand[tok * MAXC + sl] = (unsigned short)(kbase + l15);
        }
      }
    }
  }
  __syncthreads();  // the only post-stage barrier: candidates complete

  // ---- exact fp32 rescore + epilogue: 4 waves x 8 tokens ----
  float lsum = 0.f, msum = 0.f;
  for (int it = 0; it < 8; ++it) {
    int tok = wv * 8 + it;
    int n = n0 + tok;
    float4 zv = *reinterpret_cast<const float4*>(z + (size_t)n * 256 + lane * 4);
    int cnt = ccnt[tok];
    float bs = 3.4e38f; int bk = 0;
    if (cnt > MAXC) {  // overflow safety net: exact scan of all K
      for (int k = 0; k < K; ++k) {
        float4 ev = *reinterpret_cast<const float4*>(cb + (size_t)k * 256 + lane * 4);
        float dp = zv.x * ev.x + zv.y * ev.y + zv.z * ev.z + zv.w * ev.w;
        #pragma unroll
        for (int off = 32; off; off >>= 1) dp += __shfl_xor(dp, off, 64);
        float s = ee_lds[k] - 2.f * dp;
        if (s < bs) { bs = s; bk = k; }
      }
    } else {
      for (int c = 0; c < cnt; ++c) {
        int k = cand[tok * MAXC + c];
        float4 ev = *reinterpret_cast<const float4*>(cb + (size_t)k * 256 + lane * 4);
        float dp = zv.x * ev.x + zv.y * ev.y + zv.z * ev.z + zv.w * ev.w;
        #pragma unroll
        for (int off = 32; off; off >>= 1) dp += __shfl_xor(dp, off, 64);
        float s = ee_lds[k] - 2.f * dp;   // identical on all lanes
        if (s < bs || (s == bs && k < bk)) { bs = s; bk = k; }
      }
    }
    float m = mask[n];
    float4 qv = *reinterpret_cast<const float4*>(cb + (size_t)bk * 256 + lane * 4);
    float4 o; o.x = qv.x * m; o.y = qv.y * m; o.z = qv.z * m; o.w = qv.w * m;
    *reinterpret_cast<float4*>(out_q + (size_t)n * 256 + lane * 4) = o;
    float dx = zv.x - qv.x, dy = zv.y - qv.y, dz = zv.z - qv.z, dw = zv.w - qv.w;
    lsum = fmaf(m, dx * dx + dy * dy + dz * dz + dw * dw, lsum);
    if (lane == 0) {
      msum += m;
      out_idx_f[n] = (m > 0.f) ? (float)bk : 0.f;
    }
  }
  #pragma unroll
  for (int off = 32; off; off >>= 1) lsum += __shfl_down(lsum, off, 64);
  if (lane == 0) { red[wv] = lsum; red[4 + wv] = msum; }
  __syncthreads();
  if (t == 0) {
    atomicAdd(&acc2[0], red[0] + red[1] + red[2] + red[3]);
    atomicAdd(&acc2[1], red[4] + red[5] + red[6] + red[7]);
    __threadfence();
    int prev = atomicAdd(done_ctr, 1);
    last = (prev == nblocks - 1);
  }
  __syncthreads();
  if (last && t == 0) {
    float s  = atomicAdd(&acc2[0], 0.0f);
    float nv = atomicAdd(&acc2[1], 0.0f);
    out_loss[0] = (nv > 0.f) ? (0.25f * s / (nv * 256.0f)) : 0.0f;
  }
}

// ---------------------------------------------------------------------------
extern "C" void kernel_launch(void* const* d_in, const int* in_sizes, int n_in,
                              void* d_out, int out_size, void* d_ws, size_t ws_size,
                              hipStream_t stream) {
  const float* z    = (const float*)d_in[0];  // (N, 256)
  const float* mask = (const float*)d_in[1];  // (N,)
  const float* cb   = (const float*)d_in[2];  // (K, 256)
  const int N = in_sizes[1];                  // 32768
  const int D = 256;
  const int K = in_sizes[2] / D;              // 1024

  float* wsf  = (float*)d_ws;
  float* acc2 = wsf;                          // 2 floats
  int*   dctr = (int*)(wsf + 2);              // 1 int
  float* ee   = wsf + 8;                      // K floats
  unsigned short* cb_bf = (unsigned short*)(ee + K);  // K*256 bf16

  float* out_q     = (float*)d_out;           // N*D
  float* out_loss  = out_q + (size_t)N * D;   // 1
  float* out_idx_f = out_loss + 1;            // N

  vq_prep<<<(K + 3) / 4, 256, 0, stream>>>(cb, cb_bf, ee, acc2, dctr, K);
  vq_main<<<N / TOK, 256, 0, stream>>>(z, cb, cb_bf, ee, mask, out_q,
                                       out_idx_f, out_loss, acc2, dctr, N / TOK, K);
}

// Round 9
// 833.133 us; speedup vs baseline: 1.0014x; 1.0014x over previous
//
#include <hip/hip_runtime.h>
#include <cstdint>

typedef short bf16x8 __attribute__((ext_vector_type(8)));
typedef float f32x4  __attribute__((ext_vector_type(4)));

#define TOK     32        // tokens per block
#define PITCH   264       // ushorts/row (256 + 8 pad; 132 dw = 4 mod 32 -> b128 tiles banks)
#define WROWS   16        // code rows per wave-private chunk buffer
#define WSTRIDE (WROWS * PITCH)
#define MAXC    24

__device__ __forceinline__ unsigned short f2bf(float f) {
  unsigned u = __float_as_uint(f);
  return (unsigned short)((u + 0x7FFFu + ((u >> 16) & 1u)) >> 16);
}
__device__ __forceinline__ uint4 pack8(float4 a, float4 b) {
  uint4 u;
  u.x = (unsigned)f2bf(a.x) | ((unsigned)f2bf(a.y) << 16);
  u.y = (unsigned)f2bf(a.z) | ((unsigned)f2bf(a.w) << 16);
  u.z = (unsigned)f2bf(b.x) | ((unsigned)f2bf(b.y) << 16);
  u.w = (unsigned)f2bf(b.z) | ((unsigned)f2bf(b.w) << 16);
  return u;
}

// ---------------------------------------------------------------------------
// Prep: cb_bf = bf16(cb), ee = ||cb_k||^2. Block 0 zeroes global accumulators.
// ---------------------------------------------------------------------------
__global__ __launch_bounds__(256) void vq_prep(const float* __restrict__ cb,
                                               unsigned short* __restrict__ cb_bf,
                                               float* __restrict__ ee,
                                               float* __restrict__ acc2,
                                               int* __restrict__ done_ctr, int K) {
  if (blockIdx.x == 0 && threadIdx.x == 0) {
    acc2[0] = 0.f; acc2[1] = 0.f; *done_ctr = 0;
  }
  int wave = threadIdx.x >> 6, lane = threadIdx.x & 63;
  int k = blockIdx.x * 4 + wave;
  if (k >= K) return;
  float4 v = *reinterpret_cast<const float4*>(cb + (size_t)k * 256 + lane * 4);
  float s = v.x * v.x + v.y * v.y + v.z * v.z + v.w * v.w;
  #pragma unroll
  for (int off = 32; off; off >>= 1) s += __shfl_down(s, off, 64);
  ushort4 b;
  b.x = f2bf(v.x); b.y = f2bf(v.y); b.z = f2bf(v.z); b.w = f2bf(v.w);
  *reinterpret_cast<ushort4*>(cb_bf + (size_t)k * 256 + lane * 4) = b;
  if (lane == 0) ee[k] = s;
}

// ---------------------------------------------------------------------------
// Main: 256 thr (4 waves), TOK=32, grid N/32=1024 -> 4 blocks/CU (LDS 39.9 KB).
// Every wave holds BOTH A-sets (tokens 0..31) in registers and scans its own
// K-quarter (256 codes = 16 chunks of 16) in a WAVE-PRIVATE LDS buffer ->
// zero barriers in the K-loop (DS ops are wave-ordered).
// REGISTER ALLOCATION PINNED: amdgpu_waves_per_eu(4,4) = exactly 128-reg cap.
// R6/R8 lesson: launch_bounds' 2nd arg is only a MIN waves/EU — the backend
// may target MORE occupancy (64-reg cap) and spill afrag to scratch
// (VGPR_Count=64, 774-1360 us). max=4 forbids that.
// ---------------------------------------------------------------------------
__global__
__attribute__((amdgpu_flat_work_group_size(256, 256), amdgpu_waves_per_eu(4, 4)))
void vq_main(
    const float* __restrict__ z, const float* __restrict__ cb,
    const unsigned short* __restrict__ cb_bf, const float* __restrict__ ee,
    const float* __restrict__ mask,
    float* __restrict__ out_q, float* __restrict__ out_idx_f,
    float* __restrict__ out_loss, float* __restrict__ acc2,
    int* __restrict__ done_ctr, int nblocks, int K) {
  __shared__ __align__(16) unsigned short buf[4 * WSTRIDE];  // 33792 B
  __shared__ float ee_lds[1024];                             // 4096 B
  __shared__ float znorm[TOK];
  __shared__ int   ccnt[TOK];
  __shared__ unsigned short cand[TOK * MAXC];                // 1536 B
  __shared__ float red[8];
  __shared__ bool  last;

  const int t = threadIdx.x;
  const int n0 = blockIdx.x * TOK;
  const int q16 = t & 15;

  // ---- code norms into LDS ----
  ee_lds[t]       = ee[t];
  ee_lds[t + 256] = ee[t + 256];
  ee_lds[t + 512] = ee[t + 512];
  ee_lds[t + 768] = ee[t + 768];
  if (t < TOK) ccnt[t] = 0;

  // ---- stage z -> bf16 into buf rows 0..31; ||z|| ----
  #pragma unroll
  for (int pass = 0; pass < 2; ++pass) {
    int row = pass * 16 + (t >> 4);
    const float* zr = z + (size_t)(n0 + row) * 256;
    float ssq = 0.f;
    #pragma unroll
    for (int j = 0; j < 2; ++j) {
      float4 a = *reinterpret_cast<const float4*>(zr + q16 * 8 + j * 128);
      float4 b = *reinterpret_cast<const float4*>(zr + q16 * 8 + j * 128 + 4);
      ssq += a.x*a.x + a.y*a.y + a.z*a.z + a.w*a.w
           + b.x*b.x + b.y*b.y + b.z*b.z + b.w*b.w;
      *reinterpret_cast<uint4*>(&buf[row * PITCH + q16 * 8 + j * 128]) = pack8(a, b);
    }
    #pragma unroll
    for (int off = 1; off < 16; off <<= 1) ssq += __shfl_xor(ssq, off, 64);
    if (q16 == 0) znorm[row] = sqrtf(ssq);
  }
  __syncthreads();

  // ---- A fragments (both sets, tokens 0..31) into registers, all waves ----
  const int wv = t >> 6, lane = t & 63;
  const int quad = lane >> 4, l15 = lane & 15;
  bf16x8 afrag[2][8];
  float  znreg[2][4];
  #pragma unroll
  for (int s = 0; s < 2; ++s) {
    const unsigned short* za = &buf[(s * 16 + l15) * PITCH + quad * 8];
    #pragma unroll
    for (int kk = 0; kk < 8; ++kk)
      afrag[s][kk] = *reinterpret_cast<const bf16x8*>(za + kk * 32);
    #pragma unroll
    for (int r = 0; r < 4; ++r)
      znreg[s][r] = znorm[s * 16 + quad * 4 + r];
  }
  __syncthreads();  // all A-loads done before wave staging overwrites buf

  float amin[2][4];
  #pragma unroll
  for (int s = 0; s < 2; ++s)
    #pragma unroll
    for (int r = 0; r < 4; ++r) amin[s][r] = 3.4e38f;

  unsigned short* qbuf = &buf[wv * WSTRIDE];   // wave-private chunk buffer

  // ---- K-loop: 16 chunks x 16 codes, wave-private, NO barriers ----
  for (int lc = 0; lc < 16; ++lc) {
    const int kbase = wv * 256 + lc * 16;
    // stage 16 code rows (bf16): 4 rows of 16 lanes per pass, 4 passes
    #pragma unroll
    for (int pass = 0; pass < 4; ++pass) {
      int row = pass * 4 + (lane >> 4);       // 0..15
      const unsigned short* src = cb_bf + (size_t)(kbase + row) * 256;
      #pragma unroll
      for (int j = 0; j < 2; ++j) {
        uint4 v = *reinterpret_cast<const uint4*>(src + q16 * 8 + j * 128);
        *reinterpret_cast<uint4*>(&qbuf[row * PITCH + q16 * 8 + j * 128]) = v;
      }
    }
    // wave-ordered DS: reads below see this wave's writes; no __syncthreads
    f32x4 acc0 = (f32x4){0.f,0.f,0.f,0.f}, acc1 = (f32x4){0.f,0.f,0.f,0.f};
    #pragma unroll
    for (int kk = 0; kk < 8; ++kk) {
      bf16x8 b = *reinterpret_cast<const bf16x8*>(&qbuf[l15 * PITCH + quad * 8 + kk * 32]);
      acc0 = __builtin_amdgcn_mfma_f32_16x16x32_bf16(afrag[0][kk], b, acc0, 0, 0, 0);
      acc1 = __builtin_amdgcn_mfma_f32_16x16x32_bf16(afrag[1][kk], b, acc1, 0, 0, 0);
    }

    float e0  = ee_lds[kbase + l15];
    float en0 = sqrtf(e0);
    #pragma unroll
    for (int s = 0; s < 2; ++s) {
      #pragma unroll
      for (int r = 0; r < 4; ++r) {
        float d0 = e0 - 2.f * (s == 0 ? acc0[r] : acc1[r]);
        float w = d0;
        #pragma unroll
        for (int off = 1; off < 16; off <<= 1) w = fminf(w, __shfl_xor(w, off, 64));
        float am = fminf(amin[s][r], w);
        amin[s][r] = am;
        int tok = s * 16 + quad * 4 + r;
        // margin >= 2*eps(bf16 screen); quarter-local amin keeps the bound
        if (d0 <= am + 1.5f + 0.002f * znreg[s][r] * en0) {
          int sl = atomicAdd(&ccnt[tok], 1);
          if (sl < MAXC) cand[tok * MAXC + sl] = (unsigned short)(kbase + l15);
        }
      }
    }
  }
  __syncthreads();  // the only post-stage barrier: candidates complete

  // ---- exact fp32 rescore + epilogue: 4 waves x 8 tokens ----
  float lsum = 0.f, msum = 0.f;
  for (int it = 0; it < 8; ++it) {
    int tok = wv * 8 + it;
    int n = n0 + tok;
    float4 zv = *reinterpret_cast<const float4*>(z + (size_t)n * 256 + lane * 4);
    int cnt = ccnt[tok];
    float bs = 3.4e38f; int bk = 0;
    if (cnt > MAXC) {  // overflow safety net: exact scan of all K
      for (int k = 0; k < K; ++k) {
        float4 ev = *reinterpret_cast<const float4*>(cb + (size_t)k * 256 + lane * 4);
        float dp = zv.x * ev.x + zv.y * ev.y + zv.z * ev.z + zv.w * ev.w;
        #pragma unroll
        for (int off = 32; off; off >>= 1) dp += __shfl_xor(dp, off, 64);
        float s = ee_lds[k] - 2.f * dp;
        if (s < bs) { bs = s; bk = k; }
      }
    } else {
      for (int c = 0; c < cnt; ++c) {
        int k = cand[tok * MAXC + c];
        float4 ev = *reinterpret_cast<const float4*>(cb + (size_t)k * 256 + lane * 4);
        float dp = zv.x * ev.x + zv.y * ev.y + zv.z * ev.z + zv.w * ev.w;
        #pragma unroll
        for (int off = 32; off; off >>= 1) dp += __shfl_xor(dp, off, 64);
        float s = ee_lds[k] - 2.f * dp;   // identical on all lanes
        if (s < bs || (s == bs && k < bk)) { bs = s; bk = k; }
      }
    }
    float m = mask[n];
    float4 qv = *reinterpret_cast<const float4*>(cb + (size_t)bk * 256 + lane * 4);
    float4 o; o.x = qv.x * m; o.y = qv.y * m; o.z = qv.z * m; o.w = qv.w * m;
    *reinterpret_cast<float4*>(out_q + (size_t)n * 256 + lane * 4) = o;
    float dx = zv.x - qv.x, dy = zv.y - qv.y, dz = zv.z - qv.z, dw = zv.w - qv.w;
    lsum = fmaf(m, dx * dx + dy * dy + dz * dz + dw * dw, lsum);
    if (lane == 0) {
      msum += m;
      out_idx_f[n] = (m > 0.f) ? (float)bk : 0.f;
    }
  }
  #pragma unroll
  for (int off = 32; off; off >>= 1) lsum += __shfl_down(lsum, off, 64);
  if (lane == 0) { red[wv] = lsum; red[4 + wv] = msum; }
  __syncthreads();
  if (t == 0) {
    atomicAdd(&acc2[0], red[0] + red[1] + red[2] + red[3]);
    atomicAdd(&acc2[1], red[4] + red[5] + red[6] + red[7]);
    __threadfence();
    int prev = atomicAdd(done_ctr, 1);
    last = (prev == nblocks - 1);
  }
  __syncthreads();
  if (last && t == 0) {
    float s  = atomicAdd(&acc2[0], 0.0f);
    float nv = atomicAdd(&acc2[1], 0.0f);
    out_loss[0] = (nv > 0.f) ? (0.25f * s / (nv * 256.0f)) : 0.0f;
  }
}

// ---------------------------------------------------------------------------
extern "C" void kernel_launch(void* const* d_in, const int* in_sizes, int n_in,
                              void* d_out, int out_size, void* d_ws, size_t ws_size,
                              hipStream_t stream) {
  const float* z    = (const float*)d_in[0];  // (N, 256)
  const float* mask = (const float*)d_in[1];  // (N,)
  const float* cb   = (const float*)d_in[2];  // (K, 256)
  const int N = in_sizes[1];                  // 32768
  const int D = 256;
  const int K = in_sizes[2] / D;              // 1024

  float* wsf  = (float*)d_ws;
  float* acc2 = wsf;                          // 2 floats
  int*   dctr = (int*)(wsf + 2);              // 1 int
  float* ee   = wsf + 8;                      // K floats
  unsigned short* cb_bf = (unsigned short*)(ee + K);  // K*256 bf16

  float* out_q     = (float*)d_out;           // N*D
  float* out_loss  = out_q + (size_t)N * D;   // 1
  float* out_idx_f = out_loss + 1;            // N

  vq_prep<<<(K + 3) / 4, 256, 0, stream>>>(cb, cb_bf, ee, acc2, dctr, K);
  vq_main<<<N / TOK, 256, 0, stream>>>(z, cb, cb_bf, ee, mask, out_q,
                                       out_idx_f, out_loss, acc2, dctr, N / TOK, K);
}